// Round 4
// baseline (228.819 us; speedup 1.0000x reference)
//
#include <hip/hip_runtime.h>
#include <hip/hip_bf16.h>

typedef unsigned short u16;
typedef unsigned int u32;
typedef float f32x4 __attribute__((ext_vector_type(4)));
typedef short s16x8 __attribute__((ext_vector_type(8)));
typedef short s16x4 __attribute__((ext_vector_type(4)));

#define MFMA16(a, b, c) __builtin_amdgcn_mfma_f32_16x16x32_bf16(a, b, c, 0, 0, 0)

// k=16 bf16 MFMA (legacy shape, still in gfx950 HW — cdna4_isa.md §10).
// Builtin spelling varies across ROCm versions; probe, with asm fallback.
__device__ __forceinline__ f32x4 mfma_k16(s16x4 a, s16x4 b, f32x4 c) {
#if __has_builtin(__builtin_amdgcn_mfma_f32_16x16x16_bf16)
    return __builtin_amdgcn_mfma_f32_16x16x16_bf16(a, b, c, 0, 0, 0);
#elif __has_builtin(__builtin_amdgcn_mfma_f32_16x16x16bf16_1k)
    return __builtin_amdgcn_mfma_f32_16x16x16bf16_1k(a, b, c, 0, 0, 0);
#else
    f32x4 d;
    asm volatile("s_nop 1\n\tv_mfma_f32_16x16x16_bf16 %0, %1, %2, %3\n\ts_nop 1"
                 : "=v"(d) : "v"(a), "v"(b), "v"(c));
    return d;
#endif
}

#define NN 4096
#define CC 256
#define CQ 64

__device__ __forceinline__ u16 f2bf(float x) {
    union { float f; u32 u; } v; v.f = x;
    return (u16)((v.u + 0x7FFFu + ((v.u >> 16) & 1u)) >> 16);
}
// async global->LDS, 16B per lane; dst must be wave-uniform-base + lane*16 (m104)
__device__ __forceinline__ void gll16(const void* g, void* l) {
    __builtin_amdgcn_global_load_lds(
        (const __attribute__((address_space(1))) void*)g,
        (__attribute__((address_space(3))) void*)l, 16, 0, 0);
}

// ---------------------------------------------------------------------------
// prep: (a) blocks 0..1023: transpose-convert x[b][c][n] f32 -> xT[b][n][c] bf16
//       (b) blocks 1024..1119: convert Wq|Wk|Wv -> wbf[384][256] bf16
// ---------------------------------------------------------------------------
__global__ __launch_bounds__(256) void prep(
    const float* __restrict__ x, const float* __restrict__ Wq,
    const float* __restrict__ Wk, const float* __restrict__ Wv,
    u16* __restrict__ xT, u16* __restrict__ wbf)
{
    const int bid = blockIdx.x, t = threadIdx.x;
    if (bid < 1024) {
        __shared__ float tile[64 * 65];
        const int b = bid >> 8, ctile = (bid >> 6) & 3, ntile = bid & 63;
        const int c0 = ctile * 64, n0 = ntile * 64;
        const int cw = t >> 4, nj = (t & 15) * 4;
        for (int it = 0; it < 4; it++) {
            const int ci = it * 16 + cw;
            const float4 v4 = *(const float4*)(x + ((size_t)(b * CC + c0 + ci)) * NN + n0 + nj);
            tile[(nj + 0) * 65 + ci] = v4.x;
            tile[(nj + 1) * 65 + ci] = v4.y;
            tile[(nj + 2) * 65 + ci] = v4.z;
            tile[(nj + 3) * 65 + ci] = v4.w;
        }
        __syncthreads();
        const int r = t >> 2, c16 = (t & 3) * 16;
        union { u16 h[16]; uint4 q[2]; } pk;
        for (int j = 0; j < 16; j++) pk.h[j] = f2bf(tile[r * 65 + c16 + j]);
        u16* dst = xT + ((size_t)(b * NN + n0 + r)) * CC + c0 + c16;
        *(uint4*)dst = pk.q[0];
        *(uint4*)(dst + 8) = pk.q[1];
    } else {
        const int flat = (bid - 1024) * 1024 + t * 4;
        const int o = flat >> 8, c = flat & 255;
        const float* src = (o < 64)  ? (Wq + (size_t)o * CC + c)
                         : (o < 128) ? (Wk + (size_t)(o - 64) * CC + c)
                                     : (Wv + (size_t)(o - 128) * CC + c);
        const float4 v4 = *(const float4*)src;
        union { u16 h[4]; uint2 d; } pk;
        pk.h[0] = f2bf(v4.x); pk.h[1] = f2bf(v4.y);
        pk.h[2] = f2bf(v4.z); pk.h[3] = f2bf(v4.w);
        *(uint2*)(wbf + (size_t)o * CC + c) = pk.d;
    }
}

// ---------------------------------------------------------------------------
// qkv: fused projection GEMM (unchanged from R3 — passed, staging-bound small).
// ---------------------------------------------------------------------------
__global__ __launch_bounds__(256, 2) void qkv(
    const u16* __restrict__ xT, const u16* __restrict__ wbf,
    const float* __restrict__ bq, const float* __restrict__ bk,
    const float* __restrict__ bv,
    u16* __restrict__ qT, u16* __restrict__ kT, u16* __restrict__ v)
{
    __shared__ __align__(16) u16 sm[384 * 64 + 32 * 64];
    u16* Ws = sm;
    u16* Xs = sm + 384 * 64;

    const int bid = blockIdx.x;
    const int b = bid >> 7, n0 = (bid & 127) * 32;
    const int t = threadIdx.x, lane = t & 63, w = t >> 6;
    const int col = lane & 15, quad = lane >> 4;

    f32x4 acc[6][2];
    for (int i = 0; i < 6; i++) { acc[i][0] = f32x4{0,0,0,0}; acc[i][1] = f32x4{0,0,0,0}; }

    for (int cc = 0; cc < 4; cc++) {
        const int c0 = cc * 64;
        for (int m = 0; m < 12; m++) {
            const int g = w * 768 + m * 64 + lane;
            const int row = g >> 3, ch = g & 7;
            gll16(wbf + (size_t)row * CC + c0 + ((ch ^ (row & 7)) * 8),
                  Ws + (size_t)(w * 768 + m * 64) * 8 + lane * 8);
        }
        {
            const int g = w * 64 + lane;
            const int n = g >> 3, ch = g & 7;
            gll16(xT + ((size_t)(b * NN + n0 + n)) * CC + c0 + ((ch ^ (n & 7)) * 8),
                  Xs + (size_t)(w * 64) * 8 + lane * 8);
        }
        __syncthreads();
        for (int kk = 0; kk < 2; kk++) {
            s16x8 bx[2];
            for (int nt2 = 0; nt2 < 2; nt2++) {
                const int n = nt2 * 16 + col;
                bx[nt2] = *(const s16x8*)&Xs[n * 64 + (((kk * 4 + quad) ^ (n & 7)) * 8)];
            }
            for (int ot = 0; ot < 6; ot++) {
                const int row = w * 96 + ot * 16 + col;
                const s16x8 a = *(const s16x8*)&Ws[row * 64 + (((kk * 4 + quad) ^ (row & 7)) * 8)];
                acc[ot][0] = MFMA16(a, bx[0], acc[ot][0]);
                acc[ot][1] = MFMA16(a, bx[1], acc[ot][1]);
            }
        }
        __syncthreads();
    }
    for (int ot = 0; ot < 6; ot++) {
        const int og = w * 96 + ot * 16 + quad * 4;
        for (int nt2 = 0; nt2 < 2; nt2++) {
            const int n = n0 + nt2 * 16 + col;
            if (og < 64) {
                union { u16 h[4]; uint2 d; } pk;
                for (int r = 0; r < 4; r++) pk.h[r] = f2bf(acc[ot][nt2][r] + bq[og + r]);
                *(uint2*)(qT + ((size_t)(b * NN + n)) * CQ + og) = pk.d;
            } else if (og < 128) {
                union { u16 h[4]; uint2 d; } pk;
                for (int r = 0; r < 4; r++) pk.h[r] = f2bf(acc[ot][nt2][r] + bk[og - 64 + r]);
                *(uint2*)(kT + ((size_t)(b * NN + n)) * CQ + (og - 64)) = pk.d;
            } else {
                for (int r = 0; r < 4; r++)
                    v[((size_t)(b * CC + og - 128 + r)) * NN + n] =
                        f2bf(acc[ot][nt2][r] + bv[og - 128 + r]);
            }
        }
    }
}

// ---------------------------------------------------------------------------
// flash_attn v3: S^T-chaining, no P LDS round trip.
// 256 blocks x 512 thr (8 waves = 4 j-quarters x 2 c-halves), 64-row Q tile,
// 64-wide j tiles, 1 barrier/iter, K+V async double-buffered (1 iter in flight).
// Per wave per iter: S^T[its j-16][all 64 i] via 8 mfma-x32 (A=K-frag from LDS,
// B=Q-frag registers); exp+pack in-register (C-layout of S^T == A/B-layout of
// k=16 MFMA); O^T[c][i] += V-frag * P-frag via 32 mfma-k16 (V b64 from LDS).
// j-reduction of O^T partials across the 4 jq waves via LDS post-loop.
// LDS: K dbuf 2x8KB + V dbuf 2x32KB = 80KB (reused as f32 O^T buffer).
// ---------------------------------------------------------------------------
__global__ __launch_bounds__(512) void flash_attn(
    const u16* __restrict__ qT, const u16* __restrict__ kT,
    const u16* __restrict__ v, const float* __restrict__ x,
    const float* __restrict__ gamma, float* __restrict__ out)
{
    __shared__ __align__(16) u16 sm[40960];        // K: 0/4096, V: 8192/24576 (u16 units)
    __shared__ __align__(16) float ls[4][64];
    __shared__ __align__(16) float linv[64];

    const int bid = blockIdx.x;
    const int p = bid & 7;             // XCD pinning: batch b on XCDs {2b, 2b+1}
    const int b = p >> 1;
    const int n0 = ((bid >> 3) + (p & 1) * 32) * 64;
    const int t = threadIdx.x;
    const int lane = t & 63, wv = t >> 6;
    const int col = lane & 15, quad = lane >> 4;
    const int jq = wv & 3, ch = wv >> 2;

    // Q B-frags in registers (once per block): B[n=i][k=d]
    s16x8 qfrag[4][2];
    for (int it = 0; it < 4; it++) {
        const u16* qp = qT + ((size_t)(b * NN + n0 + it * 16 + col)) * CQ + quad * 8;
        qfrag[it][0] = *(const s16x8*)qp;
        qfrag[it][1] = *(const s16x8*)(qp + 32);
    }

    f32x4 o_[8][4];    // O^T partial: [ct (c=ch*128+ct*16+..)][it (i-block)]
    for (int i = 0; i < 8; i++) for (int j = 0; j < 4; j++) o_[i][j] = f32x4{0,0,0,0};
    float lac[4] = {0.f, 0.f, 0.f, 0.f};

    // staging addresses (XOR-swizzled chunks, ch^(row&7))
    const int krow = t >> 3;
    const u16* ksrc = kT + ((size_t)(b * NN + krow)) * CQ + (((t & 7) ^ (krow & 7)) * 8);
    const int kdo = t * 8;
    const u16* vsrc[4];
    int vdo[4];
    for (int m = 0; m < 4; m++) {
        const int g = m * 512 + t;
        const int row = g >> 3;
        vdo[m] = g * 8;
        vsrc[m] = v + ((size_t)(b * CC + row)) * NN + (((g & 7) ^ (row & 7)) * 8);
    }

    auto issueK = [&](int jt, int kb) {
        gll16(ksrc + (size_t)jt * 64 * CQ, sm + kb * 4096 + kdo);
    };
    auto issueV = [&](int jt, int vb) {
        u16* base = sm + 8192 + vb * 16384;
        for (int m = 0; m < 4; m++)
            gll16(vsrc[m] + jt * 64, base + vdo[m]);
    };

    issueK(0, 0);
    issueV(0, 0);
    __syncthreads();

    const int c8 = col & 7;
    for (int m = 0; m < 64; m++) {
        const int cur = m & 1;
        if (m < 63) { issueK(m + 1, cur ^ 1); issueV(m + 1, cur ^ 1); }

        // ---- S^T: D[m=j-local][n=i] ; A = K-frag (LDS), B = Q-frag (regs)
        const u16* Kb = sm + cur * 4096;
        f32x4 s[4];
        for (int it = 0; it < 4; it++) s[it] = f32x4{0,0,0,0};
        for (int kk = 0; kk < 2; kk++) {
            const s16x8 a = *(const s16x8*)
                &Kb[(jq * 16 + col) * 64 + (((kk * 4 + quad) ^ c8) * 8)];
            for (int it = 0; it < 4; it++)
                s[it] = MFMA16(a, qfrag[it][kk], s[it]);
        }
        // ---- exp + pack: lane holds P[i=it*16+col][j=j0+jq*16+quad*4+r]
        s16x4 pfrag[4];
        for (int it = 0; it < 4; it++) {
            union { u16 h[4]; s16x4 v4; } pk;
            for (int r = 0; r < 4; r++) {
                const float pv = __expf(fminf(s[it][r], 60.f));
                lac[it] += pv;
                pk.h[r] = f2bf(pv);
            }
            pfrag[it] = pk.v4;
        }
        // ---- O^T += V-frag * P-frag (k=16); V-frag b64, reused over 4 i-tiles
        const u16* Vb = sm + 8192 + cur * 16384;
        const int lch = jq * 2 + (quad >> 1), sub = (quad & 1) * 4;
        for (int ct = 0; ct < 8; ct++) {
            const int c = ch * 128 + ct * 16 + col;
            const s16x4 va = *(const s16x4*)&Vb[c * 64 + ((lch ^ c8) * 8) + sub];
            for (int it = 0; it < 4; it++)
                o_[ct][it] = mfma_k16(va, pfrag[it], o_[ct][it]);
        }
        __syncthreads();   // drains next-iter DMAs; releases cur buffers
    }

    // ---- l: sum over quads (j within jq), publish per-jq
    for (int it = 0; it < 4; it++) {
        float lv = lac[it];
        lv += __shfl_xor(lv, 16, 64);
        lv += __shfl_xor(lv, 32, 64);
        lac[it] = lv;
    }
    if (ch == 0 && quad == 0)
        for (int it = 0; it < 4; it++) ls[jq][it * 16 + col] = lac[it];

    // ---- O^T j-reduction across jq waves through LDS (f32, stride 68)
    float* F = (float*)sm;
    const int fb = ch * 8704;
    for (int s = 0; s < 4; s++) {
        __syncthreads();
        if (jq == s) {
            for (int ct = 0; ct < 8; ct++)
                for (int it = 0; it < 4; it++)
                    for (int r = 0; r < 4; r++) {
                        const int addr = fb + (ct * 16 + quad * 4 + r) * 68 + it * 16 + col;
                        if (s == 0) F[addr] = o_[ct][it][r];
                        else        F[addr] += o_[ct][it][r];
                    }
        }
    }
    __syncthreads();
    if (t < 64)
        linv[t] = gamma[0] / (ls[0][t] + ls[1][t] + ls[2][t] + ls[3][t]);
    __syncthreads();

    // ---- out[b][c][n0+i] = x + linv[i] * O^T[c][i], coalesced float4
    for (int it = 0; it < 4; it++) {
        const int c = (t >> 3) + it * 64;
        const int n8 = (t & 7) * 8;
        const float* Fr = F + (c >> 7) * 8704 + (c & 127) * 68 + n8;
        const float4 l0 = *(const float4*)&linv[n8];
        const float4 l1 = *(const float4*)&linv[n8 + 4];
        const float4 f0 = *(const float4*)Fr;
        const float4 f1 = *(const float4*)(Fr + 4);
        const float* xp = x + ((size_t)(b * CC + c)) * NN + n0 + n8;
        float* op = out + ((size_t)(b * CC + c)) * NN + n0 + n8;
        const float4 x0 = *(const float4*)xp;
        const float4 x1 = *(const float4*)(xp + 4);
        float4 r0, r1;
        r0.x = x0.x + f0.x * l0.x; r0.y = x0.y + f0.y * l0.y;
        r0.z = x0.z + f0.z * l0.z; r0.w = x0.w + f0.w * l0.w;
        r1.x = x1.x + f1.x * l1.x; r1.y = x1.y + f1.y * l1.y;
        r1.z = x1.z + f1.z * l1.z; r1.w = x1.w + f1.w * l1.w;
        *(float4*)op = r0;
        *(float4*)(op + 4) = r1;
    }
}

// ---------------------------------------------------------------------------
extern "C" void kernel_launch(void* const* d_in, const int* in_sizes, int n_in,
                              void* d_out, int out_size, void* d_ws, size_t ws_size,
                              hipStream_t stream)
{
    const float* x     = (const float*)d_in[0];
    const float* Wq    = (const float*)d_in[1];
    const float* bq    = (const float*)d_in[2];
    const float* Wk    = (const float*)d_in[3];
    const float* bk    = (const float*)d_in[4];
    const float* Wv    = (const float*)d_in[5];
    const float* bv    = (const float*)d_in[6];
    const float* gamma = (const float*)d_in[7];
    float* out = (float*)d_out;

    u16* xT  = (u16*)d_ws;
    u16* wbf = xT  + (size_t)4 * NN * CC;
    u16* qTw = wbf + (size_t)384 * CC;
    u16* kTw = qTw + (size_t)4 * NN * CQ;
    u16* vw  = kTw + (size_t)4 * NN * CQ;

    prep<<<1120, 256, 0, stream>>>(x, Wq, Wk, Wv, xT, wbf);
    qkv<<<512, 256, 0, stream>>>(xT, wbf, bq, bk, bv, qTw, kTw, vw);
    flash_attn<<<256, 512, 0, stream>>>(qTw, kTw, vw, x, gamma, out);
}

// Round 5
// 169.915 us; speedup vs baseline: 1.3467x; 1.3467x over previous
//
#include <hip/hip_runtime.h>
#include <hip/hip_bf16.h>

typedef unsigned short u16;
typedef unsigned int u32;
typedef float f32x4 __attribute__((ext_vector_type(4)));
typedef short s16x8 __attribute__((ext_vector_type(8)));

#define MFMA16(a, b, c) __builtin_amdgcn_mfma_f32_16x16x32_bf16(a, b, c, 0, 0, 0)

#define NN 4096
#define CC 256
#define CQ 64

__device__ __forceinline__ u16 f2bf(float x) {
    union { float f; u32 u; } v; v.f = x;
    return (u16)((v.u + 0x7FFFu + ((v.u >> 16) & 1u)) >> 16);
}
__device__ __forceinline__ float bf2f(u16 u) {
    union { u32 u; float f; } v; v.u = ((u32)u) << 16;
    return v.f;
}
// async global->LDS, 16B/lane; dst = wave-uniform base + lane*16 (m104)
__device__ __forceinline__ void gll16(const void* g, void* l) {
    __builtin_amdgcn_global_load_lds(
        (const __attribute__((address_space(1))) void*)g,
        (__attribute__((address_space(3))) void*)l, 16, 0, 0);
}

// ---------------------------------------------------------------------------
// prep: blocks 0..1023: x[b][c][n] f32 -> xT[b][n][c] bf16 (LDS transpose)
//       blocks 1024..1119: Wq|Wk|Wv f32 -> wbf[384][256] bf16
// ---------------------------------------------------------------------------
__global__ __launch_bounds__(256) void prep(
    const float* __restrict__ x, const float* __restrict__ Wq,
    const float* __restrict__ Wk, const float* __restrict__ Wv,
    u16* __restrict__ xT, u16* __restrict__ wbf)
{
    const int bid = blockIdx.x, t = threadIdx.x;
    if (bid < 1024) {
        __shared__ float tile[64 * 65];
        const int b = bid >> 8, ctile = (bid >> 6) & 3, ntile = bid & 63;
        const int c0 = ctile * 64, n0 = ntile * 64;
        const int cw = t >> 4, nj = (t & 15) * 4;
        for (int it = 0; it < 4; it++) {
            const int ci = it * 16 + cw;
            const float4 v4 = *(const float4*)(x + ((size_t)(b * CC + c0 + ci)) * NN + n0 + nj);
            tile[(nj + 0) * 65 + ci] = v4.x;
            tile[(nj + 1) * 65 + ci] = v4.y;
            tile[(nj + 2) * 65 + ci] = v4.z;
            tile[(nj + 3) * 65 + ci] = v4.w;
        }
        __syncthreads();
        const int r = t >> 2, c16 = (t & 3) * 16;
        union { u16 h[16]; uint4 q[2]; } pk;
        for (int j = 0; j < 16; j++) pk.h[j] = f2bf(tile[r * 65 + c16 + j]);
        u16* dst = xT + ((size_t)(b * NN + n0 + r)) * CC + c0 + c16;
        *(uint4*)dst = pk.q[0];
        *(uint4*)(dst + 8) = pk.q[1];
    } else {
        const int flat = (bid - 1024) * 1024 + t * 4;
        const int o = flat >> 8, c = flat & 255;
        const float* src = (o < 64)  ? (Wq + (size_t)o * CC + c)
                         : (o < 128) ? (Wk + (size_t)(o - 64) * CC + c)
                                     : (Wv + (size_t)(o - 128) * CC + c);
        const float4 v4 = *(const float4*)src;
        union { u16 h[4]; uint2 d; } pk;
        pk.h[0] = f2bf(v4.x); pk.h[1] = f2bf(v4.y);
        pk.h[2] = f2bf(v4.z); pk.h[3] = f2bf(v4.w);
        *(uint2*)(wbf + (size_t)o * CC + c) = pk.d;
    }
}

// ---------------------------------------------------------------------------
// qkv v2: 512 blocks (2/CU) x 512 thr (8 waves; 16 waves/CU). n-tile 32.
// Each wave: 48 W-rows (3 o-tiles) x 32 n. Async swizzled staging.
// ---------------------------------------------------------------------------
__global__ __launch_bounds__(512, 4) void qkv(
    const u16* __restrict__ xT, const u16* __restrict__ wbf,
    const float* __restrict__ bq, const float* __restrict__ bk,
    const float* __restrict__ bv,
    u16* __restrict__ qT, u16* __restrict__ kT, u16* __restrict__ v)
{
    __shared__ __align__(16) u16 sm[384 * 64 + 32 * 64];  // 53248 B
    u16* Ws = sm;             // [384][64] swizzled
    u16* Xs = sm + 384 * 64;  // [32][64] swizzled

    const int bid = blockIdx.x;
    const int b = bid >> 7, n0 = (bid & 127) * 32;
    const int t = threadIdx.x, lane = t & 63, w = t >> 6;
    const int col = lane & 15, quad = lane >> 4;

    f32x4 acc[3][2];
    for (int i = 0; i < 3; i++) { acc[i][0] = f32x4{0,0,0,0}; acc[i][1] = f32x4{0,0,0,0}; }

    for (int cc = 0; cc < 4; cc++) {
        const int c0 = cc * 64;
        for (int m = 0; m < 6; m++) {
            const int g = m * 512 + t;
            const int row = g >> 3, ch = g & 7;
            gll16(wbf + (size_t)row * CC + c0 + ((ch ^ (row & 7)) * 8), Ws + g * 8);
        }
        if (w < 4) {
            const int g = w * 64 + lane;
            const int n = g >> 3, ch = g & 7;
            gll16(xT + ((size_t)(b * NN + n0 + n)) * CC + c0 + ((ch ^ (n & 7)) * 8),
                  Xs + g * 8);
        }
        __syncthreads();
        for (int kk = 0; kk < 2; kk++) {
            s16x8 bx[2];
            for (int nt2 = 0; nt2 < 2; nt2++) {
                const int n = nt2 * 16 + col;
                bx[nt2] = *(const s16x8*)&Xs[n * 64 + (((kk * 4 + quad) ^ (n & 7)) * 8)];
            }
            for (int ot = 0; ot < 3; ot++) {
                const int row = w * 48 + ot * 16 + col;
                const s16x8 a = *(const s16x8*)&Ws[row * 64 + (((kk * 4 + quad) ^ (row & 7)) * 8)];
                acc[ot][0] = MFMA16(a, bx[0], acc[ot][0]);
                acc[ot][1] = MFMA16(a, bx[1], acc[ot][1]);
            }
        }
        __syncthreads();
    }
    for (int ot = 0; ot < 3; ot++) {
        const int og = w * 48 + ot * 16 + quad * 4;   // wave-uniform 16-aligned region
        for (int nt2 = 0; nt2 < 2; nt2++) {
            const int n = n0 + nt2 * 16 + col;
            if (og < 64) {
                union { u16 h[4]; uint2 d; } pk;
                for (int r = 0; r < 4; r++) pk.h[r] = f2bf(acc[ot][nt2][r] + bq[og + r]);
                *(uint2*)(qT + ((size_t)(b * NN + n)) * CQ + og) = pk.d;
            } else if (og < 128) {
                union { u16 h[4]; uint2 d; } pk;
                for (int r = 0; r < 4; r++) pk.h[r] = f2bf(acc[ot][nt2][r] + bk[og - 64 + r]);
                *(uint2*)(kT + ((size_t)(b * NN + n)) * CQ + (og - 64)) = pk.d;
            } else {
                for (int r = 0; r < 4; r++)
                    v[((size_t)(b * CC + og - 128 + r)) * NN + n] =
                        f2bf(acc[ot][nt2][r] + bv[og - 128 + r]);
            }
        }
    }
}

// ---------------------------------------------------------------------------
// flash_attn v4: j-split x2 for 2 blocks/CU. 512 blocks x 512 thr.
// Block (b, qt, jh): Q-tile 64 rows, j in [jh*2048, +2048), 64 iters of 32 j.
// v2's skewed 1-barrier pipeline: K dbuf 2x4KB, V dbuf 2x16KB, P dbuf 2x5KB
// (51.2KB -> 2 blocks/CU co-resident). No-max softmax => partials additive:
// jh=0 writes bf16 partial O to Op0 (+ l to lws), jh=1 writes f32 partial to
// d_out. combine() finishes: out = x + g*(O0+O1)/(l0+l1).
// Waves: S role (strip=w&3, jhalf_in=w>>2), PV role (ih=w>>2, cq=w&3).
// ---------------------------------------------------------------------------
__global__ __launch_bounds__(512, 4) void flash_attn(
    const u16* __restrict__ qT, const u16* __restrict__ kT,
    const u16* __restrict__ v,
    u16* __restrict__ Op0, float* __restrict__ Op1,
    float* __restrict__ lws)
{
    // u16 offsets: K0@0 K1@2048 | V0@4096 V1@12288 | P0@20480 P1@23040 (stride 40)
    __shared__ __align__(16) u16 sm[25600];   // 51200 B
    __shared__ float ls[2][64];

    const int bid = blockIdx.x;
    const int p = bid & 7;                 // XCD pin: (b, jh) per XCD, K/V-half in L2
    const int b = p >> 1, jh = p & 1;
    const int n0 = (bid >> 3) * 64;
    const int jb = jh * 2048;
    const int t = threadIdx.x;
    const int lane = t & 63, wv = t >> 6;
    const int col = lane & 15, quad = lane >> 4;
    const int strip = wv & 3, jhi = wv >> 2;   // S-phase identity
    const int ih = wv >> 2, cq = wv & 3;       // PV-phase identity

    // Q A-frags for S (A[m=i]: row = n0 + strip*16 + col)
    s16x8 aq[2];
    {
        const u16* qp = qT + ((size_t)(b * NN + n0 + strip * 16 + col)) * CQ + quad * 8;
        aq[0] = *(const s16x8*)qp;
        aq[1] = *(const s16x8*)(qp + 32);
    }

    f32x4 o_[2][4];    // D[m=i (quad*4+r), n=c (col)]: [it2 strip][ct c-tile]
    for (int i = 0; i < 2; i++) for (int j = 0; j < 4; j++) o_[i][j] = f32x4{0,0,0,0};
    float lac[4] = {0.f, 0.f, 0.f, 0.f};

    // staging addresses (K: 256 chunks via waves 0-3; V: 1024 chunks, 2/thread)
    const int kg = wv * 64 + lane;             // valid for wv<4
    const int krow = kg >> 3;
    const u16* ksrc = kT + ((size_t)(b * NN + jb + krow)) * CQ + (((kg & 7) ^ (krow & 7)) * 8);
    const int kdo = kg * 8;
    const u16* vsrc[2];
    int vdo[2];
    for (int m = 0; m < 2; m++) {
        const int g = m * 512 + t;
        const int row = g >> 2;                // 4 chunks per 32-j row
        vdo[m] = g * 8;
        vsrc[m] = v + ((size_t)(b * CC + row)) * NN + jb + (g & 3) * 8;
    }

    auto issueK = [&](int jt, int kb) {
        if (wv < 4) gll16(ksrc + (size_t)jt * 32 * CQ, sm + kb * 2048 + kdo);
    };
    auto issueV = [&](int jt, int vb) {
        u16* base = sm + 4096 + vb * 8192;
        for (int m = 0; m < 2; m++)
            gll16(vsrc[m] + jt * 32, base + vdo[m]);
    };
    auto S_phase = [&](int kb, int pb) {
        const u16* Kb = sm + kb * 2048;
        u16* Pb = sm + 20480 + pb * 2560;
        f32x4 s = f32x4{0,0,0,0};
        for (int kk = 0; kk < 2; kk++) {
            const int jrow = jhi * 16 + col;
            const s16x8 bk_ = *(const s16x8*)
                &Kb[jrow * 64 + (((kk * 4 + quad) ^ (jrow & 7)) * 8)];
            s = MFMA16(aq[kk], bk_, s);
        }
        for (int r = 0; r < 4; r++) {
            const float pv = __expf(fminf(s[r], 60.f));
            lac[r] += pv;
            Pb[(strip * 16 + quad * 4 + r) * 40 + jhi * 16 + col] = f2bf(pv);
        }
    };
    auto PV_phase = [&](int pb, int vb) {
        const u16* Pb = sm + 20480 + pb * 2560;
        const u16* Vb = sm + 4096 + vb * 8192;
        s16x8 pa[2];
        for (int it2 = 0; it2 < 2; it2++)
            pa[it2] = *(const s16x8*)&Pb[((ih * 2 + it2) * 16 + col) * 40 + quad * 8];
        for (int ct = 0; ct < 4; ct++) {
            const int c = cq * 64 + ct * 16 + col;
            const s16x8 bv_ = *(const s16x8*)&Vb[c * 32 + quad * 8];
            o_[0][ct] = MFMA16(pa[0], bv_, o_[0][ct]);
            o_[1][ct] = MFMA16(pa[1], bv_, o_[1][ct]);
        }
    };

    // skewed 1-barrier pipeline (v2 schedule at half tile)
    issueK(0, 0);
    issueV(0, 0);
    issueK(1, 1);
    __syncthreads();
    S_phase(0, 0);

    int vcur = 0, pcur = 0;
    for (int m = 0; m < 64; m++) {
        __syncthreads();      // drains prior-iter DMAs; P[pcur] visible
        issueV((m + 1 < 64) ? m + 1 : 63, vcur ^ 1);
        issueK((m + 2 < 64) ? m + 2 : 63, m & 1);
        PV_phase(pcur, vcur);
        if (m < 63) S_phase((m + 1) & 1, pcur ^ 1);
        vcur ^= 1; pcur ^= 1;
    }

    // ---- l: reduce over this wave's 16 j-cols, publish per jhi half
    for (int r = 0; r < 4; r++) {
        float lv = lac[r];
        lv += __shfl_xor(lv, 1, 64);
        lv += __shfl_xor(lv, 2, 64);
        lv += __shfl_xor(lv, 4, 64);
        lv += __shfl_xor(lv, 8, 64);
        lac[r] = lv;
    }
    if (col == 0)
        for (int r = 0; r < 4; r++)
            ls[jhi][strip * 16 + quad * 4 + r] = lac[r];
    __syncthreads();   // drains trailing DMAs before sm reuse; ls visible
    if (t < 64)
        lws[(size_t)jh * 4 * NN + (size_t)b * NN + n0 + t] = ls[0][t] + ls[1][t];

    // ---- epilogue: transpose O through LDS in 2 rounds of 128 c
    float* Tf = (float*)sm;    // [128][68] f32 (34.8KB)
    u16*  Tu = sm;             // [128][136] u16
    for (int rd = 0; rd < 2; rd++) {
        if ((cq >> 1) == rd) {
            const int cl = (cq & 1) * 64;
            for (int it2 = 0; it2 < 2; it2++) {
                const int ib = (ih * 2 + it2) * 16 + quad * 4;
                for (int ct = 0; ct < 4; ct++) {
                    const int c = cl + ct * 16 + col;
                    if (jh == 0) {
                        union { u16 h[4]; uint2 d; } pk;
                        for (int r = 0; r < 4; r++) pk.h[r] = f2bf(o_[it2][ct][r]);
                        *(uint2*)&Tu[c * 136 + ib] = pk.d;
                    } else {
                        *(float2*)&Tf[c * 68 + ib] = float2{o_[it2][ct][0], o_[it2][ct][1]};
                        *(float2*)&Tf[c * 68 + ib + 2] = float2{o_[it2][ct][2], o_[it2][ct][3]};
                    }
                }
            }
        }
        __syncthreads();
        const int cl = t >> 2, i0 = (t & 3) * 16;
        const int c = rd * 128 + cl;
        if (jh == 0) {
            u16* dst = Op0 + ((size_t)(b * CC + c)) * NN + n0 + i0;
            *(uint4*)dst       = *(const uint4*)&Tu[cl * 136 + i0];
            *(uint4*)(dst + 8) = *(const uint4*)&Tu[cl * 136 + i0 + 8];
        } else {
            float* dst = Op1 + ((size_t)(b * CC + c)) * NN + n0 + i0;
            for (int k = 0; k < 4; k++)
                *(float4*)(dst + k * 4) = *(const float4*)&Tf[cl * 68 + i0 + k * 4];
        }
        __syncthreads();
    }
}

// ---------------------------------------------------------------------------
// combine: out = x + gamma * (O0 + O1) / (l0 + l1)   (in-place over d_out=O1)
// ---------------------------------------------------------------------------
__global__ __launch_bounds__(256) void combine(
    const float* __restrict__ x, const u16* __restrict__ Op0,
    const float* __restrict__ lws, const float* __restrict__ gamma,
    float* __restrict__ out)
{
    const size_t idx = ((size_t)blockIdx.x * 256 + threadIdx.x) * 4;
    const int b = (int)(idx >> 20);
    const int n = (int)(idx & (NN - 1));
    const float g = gamma[0];
    const float4 xv = *(const float4*)(x + idx);
    const float4 o1 = *(const float4*)(out + idx);
    const u16* o0p = Op0 + idx;
    const float4 l0 = *(const float4*)(lws + (size_t)b * NN + n);
    const float4 l1 = *(const float4*)(lws + (size_t)4 * NN + (size_t)b * NN + n);
    float4 r;
    r.x = xv.x + g * (bf2f(o0p[0]) + o1.x) / (l0.x + l1.x);
    r.y = xv.y + g * (bf2f(o0p[1]) + o1.y) / (l0.y + l1.y);
    r.z = xv.z + g * (bf2f(o0p[2]) + o1.z) / (l0.z + l1.z);
    r.w = xv.w + g * (bf2f(o0p[3]) + o1.w) / (l0.w + l1.w);
    *(float4*)(out + idx) = r;
}

// ---------------------------------------------------------------------------
extern "C" void kernel_launch(void* const* d_in, const int* in_sizes, int n_in,
                              void* d_out, int out_size, void* d_ws, size_t ws_size,
                              hipStream_t stream)
{
    const float* x     = (const float*)d_in[0];
    const float* Wq    = (const float*)d_in[1];
    const float* bq    = (const float*)d_in[2];
    const float* Wk    = (const float*)d_in[3];
    const float* bk    = (const float*)d_in[4];
    const float* Wv    = (const float*)d_in[5];
    const float* bv    = (const float*)d_in[6];
    const float* gamma = (const float*)d_in[7];
    float* out = (float*)d_out;

    // ws (u16): xT 8.4MB (reused as Op0) | wbf 196KB (reused as lws 128KB)
    //           | qT 2.1MB | kT 2.1MB | v 8.4MB  — total ~21.2MB (same as R3)
    u16* xT  = (u16*)d_ws;
    u16* wbf = xT  + (size_t)4 * NN * CC;
    u16* qTw = wbf + (size_t)384 * CC;
    u16* kTw = qTw + (size_t)4 * NN * CQ;
    u16* vw  = kTw + (size_t)4 * NN * CQ;
    u16* Op0 = xT;                 // xT dead after qkv
    float* lws = (float*)wbf;      // wbf dead after qkv

    prep<<<1120, 256, 0, stream>>>(x, Wq, Wk, Wv, xT, wbf);
    qkv<<<512, 512, 0, stream>>>(xT, wbf, bq, bk, bv, qTw, kTw, vw);
    flash_attn<<<512, 512, 0, stream>>>(qTw, kTw, vw, Op0, out, lws);
    combine<<<4096, 256, 0, stream>>>(x, Op0, lws, gamma, out);
}